// Round 5
// baseline (220.176 us; speedup 1.0000x reference)
//
#include <hip/hip_runtime.h>
#include <hip/hip_bf16.h>

#define TSEQ 2048
#define CEMB 1024

typedef __attribute__((ext_vector_type(8))) short bf16x8;
typedef __attribute__((ext_vector_type(4))) float f32x4;
typedef __attribute__((ext_vector_type(16))) float f32x16;
typedef __attribute__((ext_vector_type(4))) int i32x4;

__device__ __forceinline__ unsigned short f2bf(float f){
  return __builtin_bit_cast(unsigned short, __float2bfloat16(f));
}

// ---------- f32 -> bf16 elementwise (4 elems/thread) ----------
__global__ void k_cvt_bf16(const float* __restrict__ in, unsigned short* __restrict__ out, int n4){
  int i = blockIdx.x * blockDim.x + threadIdx.x;
  if (i >= n4) return;
  const float4 v = reinterpret_cast<const float4*>(in)[i];
  ushort4 o;
  o.x = f2bf(v.x); o.y = f2bf(v.y); o.z = f2bf(v.z); o.w = f2bf(v.w);
  reinterpret_cast<ushort4*>(out)[i] = o;
}

// ---------- transpose + convert: w [K,N] f32 -> wT [N,K] bf16 ----------
__global__ void k_transpose_bf16(const float* __restrict__ w, unsigned short* __restrict__ wT, int K, int N){
  __shared__ unsigned short tile[32][33];
  const int n0 = blockIdx.x * 32, k0 = blockIdx.y * 32;
  const int tx = threadIdx.x & 31, ty = threadIdx.x >> 5; // ty 0..7
  #pragma unroll
  for (int r = 0; r < 4; ++r){
    int k = ty * 4 + r;
    tile[k][tx] = f2bf(w[(size_t)(k0 + k) * N + n0 + tx]);
  }
  __syncthreads();
  #pragma unroll
  for (int r = 0; r < 4; ++r){
    int n = ty * 4 + r;
    wT[(size_t)(n0 + n) * K + k0 + tx] = tile[tx][n];
  }
}

// ---------- V head-transpose: qkv[t][2048+h*64+d] -> vT[(bh*64+d)][t] ----------
__global__ __launch_bounds__(256) void k_vT(const unsigned short* __restrict__ qkv,
                                            unsigned short* __restrict__ vT){
  __shared__ __align__(16) unsigned short tile[64*64];
  const int tid = threadIdx.x;
  const int bh = blockIdx.x;          // b*16+h
  const int t0 = blockIdx.y * 64;
  const int b = bh >> 4, h = bh & 15;
  const int lt = tid >> 3, seg = tid & 7;
  #pragma unroll
  for (int r = 0; r < 2; ++r){
    const int t = lt + 32*r;
    const i32x4 v = *(const i32x4*)&qkv[((size_t)(b*TSEQ + t0 + t))*3072 + 2048 + h*64 + seg*8];
    const int slot = seg ^ (t & 7) ^ (t >> 3);
    *(i32x4*)((char*)tile + t*128 + slot*16) = v;
  }
  __syncthreads();
  const int w = tid >> 6, lane = tid & 63;
  const int tseg = lane & 7;
  #pragma unroll
  for (int r = 0; r < 2; ++r){
    const int d = w*8 + (lane>>3) + 32*r;
    unsigned int wd[4];
    #pragma unroll
    for (int jp = 0; jp < 4; ++jp){
      unsigned int lo, hi;
      #pragma unroll
      for (int e = 0; e < 2; ++e){
        const int j = jp*2 + e;
        const int t = tseg*8 + j;
        const int byteoff = t*128 + ((2*d) ^ (((j ^ tseg) & 7) << 4));
        const unsigned int val = *(const unsigned short*)((const char*)tile + byteoff);
        if (e == 0) lo = val; else hi = val;
      }
      wd[jp] = lo | (hi << 16);
    }
    i32x4 o4; o4[0]=wd[0]; o4[1]=wd[1]; o4[2]=wd[2]; o4[3]=wd[3];
    *(i32x4*)&vT[((size_t)bh*64 + d)*2048 + t0 + tseg*8] = o4;
  }
}

// ---------- GEMM: C[M,N] = A[M,K](bf16) * Bt[N,K](bf16)^T + bias ----------
// m97 structure + T1 bijective XCD swizzle (m204).
template<bool OUT_BF16>
__global__ __launch_bounds__(256) void k_gemm_bt(
    const unsigned short* __restrict__ A,
    const unsigned short* __restrict__ Bt,
    const float* __restrict__ bias,
    void* __restrict__ Cout, int M, int N, int K)
{
  __shared__ __align__(16) unsigned short As[128*32];
  __shared__ __align__(16) unsigned short Bs[128*32];
  const int tid = threadIdx.x;
  const int lane = tid & 63, w = tid >> 6;
  const int wr = w >> 1, wc = w & 1;
  const int l15 = lane & 15, l4 = lane >> 4;

  // T1: bijective XCD-aware remap of the flattened block id
  const unsigned nwg = gridDim.x * gridDim.y;
  unsigned lin = blockIdx.y * gridDim.x + blockIdx.x;
  {
    const unsigned qq = nwg >> 3, rr = nwg & 7;
    const unsigned xcd = lin & 7, loc = lin >> 3;
    lin = (xcd < rr ? xcd * (qq + 1) : rr * (qq + 1) + (xcd - rr) * qq) + loc;
  }
  const int m0 = (int)(lin / gridDim.x) * 128;
  const int n0 = (int)(lin % gridDim.x) * 128;

  const unsigned short* Ag = A + (size_t)(m0 + (tid >> 2)) * K + (tid & 3) * 8;
  const unsigned short* Bg = Bt + (size_t)(n0 + (tid >> 2)) * K + (tid & 3) * 8;

  f32x4 acc[4][4] = {};

  for (int kk = 0; kk < K; kk += 32){
    #pragma unroll
    for (int rd = 0; rd < 2; ++rd){
      __builtin_amdgcn_global_load_lds(
        (const __attribute__((address_space(1))) void*)(Ag + kk + (size_t)rd * 64 * K),
        (__attribute__((address_space(3))) void*)&As[(rd * 256 + w * 64) * 8],
        16, 0, 0);
      __builtin_amdgcn_global_load_lds(
        (const __attribute__((address_space(1))) void*)(Bg + kk + (size_t)rd * 64 * K),
        (__attribute__((address_space(3))) void*)&Bs[(rd * 256 + w * 64) * 8],
        16, 0, 0);
    }
    __syncthreads();
    bf16x8 af[4], bfr[4];
    #pragma unroll
    for (int m = 0; m < 4; ++m)
      af[m] = *(const bf16x8*)&As[(wr*64 + m*16 + l15) * 32 + l4*8];
    #pragma unroll
    for (int n = 0; n < 4; ++n)
      bfr[n] = *(const bf16x8*)&Bs[(wc*64 + n*16 + l15) * 32 + l4*8];
    #pragma unroll
    for (int m = 0; m < 4; ++m){
      #pragma unroll
      for (int n = 0; n < 4; ++n)
        acc[m][n] = __builtin_amdgcn_mfma_f32_16x16x32_bf16(af[m], bfr[n], acc[m][n], 0, 0, 0);
    }
    __syncthreads();
  }

  float bv[4];
  #pragma unroll
  for (int n = 0; n < 4; ++n) bv[n] = bias[n0 + wc*64 + n*16 + l15];

  #pragma unroll
  for (int m = 0; m < 4; ++m){
    const int row = m0 + wr*64 + m*16 + l4*4;
    #pragma unroll
    for (int n = 0; n < 4; ++n){
      const int col = n0 + wc*64 + n*16 + l15;
      #pragma unroll
      for (int r = 0; r < 4; ++r){
        float v = acc[m][n][r] + bv[n];
        if (OUT_BF16)
          ((unsigned short*)Cout)[(size_t)(row + r) * N + col] = f2bf(v);
        else
          ((float*)Cout)[(size_t)(row + r) * N + col] = v;
      }
    }
  }
}

// ---------- causal flash attention v5 ----------
// Folded-diagonal pairing: block (bh, p) handles q-tiles tA=p and tB=15-p
// with SHARED K/V staging -> all 512 blocks have equal MFMA work (no tail).
// Swapped QK^T (32x32x16), softmax in-register with Q pre-scaled by
// (1/sqrt(D))*log2e (no per-score scale/shift; normalization cancels),
// T12 cvt_pk+permlane packing, direct global_load_lds double-buffer,
// ONE barrier per 64-key tile.
__global__ __launch_bounds__(256) void k_attn(
    const unsigned short* __restrict__ qkv,
    const unsigned short* __restrict__ vT,
    unsigned short* __restrict__ y)
{
  __shared__ __align__(16) char Ksm[2][8192];   // [key 64][128B], slot^=(key&7)
  __shared__ __align__(16) char Vsm[2][8192];   // [d 64][128B],  slot^=(d&7)
  __shared__ float Ls[2][4][32];

  const int tid = threadIdx.x, lane = tid & 63, w = tid >> 6;
  const int q31 = lane & 31, hi = lane >> 5;
  const int bh = blockIdx.x, p = blockIdx.y;    // p in [0,8)
  const int tA = p, tB = 15 - p;                // nktA<=16 < nktB>=18
  const int b = bh >> 4, h = bh & 15;
  const size_t rowB = (size_t)b * TSEQ;

  const int wq0A = tA*128 + 32*w, qgA = wq0A + q31;
  const int wq0B = tB*128 + 32*w, qgB = wq0B + q31;

  const float sc = 0.18033688011112042f;   // (1/sqrt(64)) * log2(e)

  // hoisted Q as B-fragments, PRE-SCALED by sc (folds softmax scale into MFMA)
  bf16x8 qfA[4], qfB[4];
  #pragma unroll
  for (int t = 0; t < 2; ++t){
    const unsigned short* qp = qkv + (rowB + (t ? qgB : qgA)) * 3072 + h * 64;
    #pragma unroll
    for (int c4 = 0; c4 < 4; ++c4){
      bf16x8 v = *(const bf16x8*)(qp + c4*16 + hi*8);
      #pragma unroll
      for (int j = 0; j < 8; ++j){
        const unsigned int bits = ((unsigned int)(unsigned short)v[j]) << 16;
        v[j] = (short)f2bf(__builtin_bit_cast(float, bits) * sc);
      }
      if (t) qfB[c4] = v; else qfA[c4] = v;
    }
  }

  // staging geometry (per lane): row kr, slot sl, content-chunk cx = sl^kr
  const int kr = lane >> 3, sl = lane & 7, cx = sl ^ kr;
  const unsigned short* kgbase = qkv + (rowB + w*8 + kr) * 3072 + 1024 + h*64 + cx*8;
  const unsigned short* vgbase = vT + ((size_t)bh*64 + w*8 + kr) * 2048 + cx*8;

  #define STAGE(ktile, buf)                                                          \
    do {                                                                             \
      char* kb_ = &Ksm[buf][0] + w*1024;                                             \
      char* vb_ = &Vsm[buf][0] + w*1024;                                             \
      const unsigned short* ks_ = kgbase + (size_t)(ktile)*64*3072;                  \
      const unsigned short* vs_ = vgbase + (ktile)*64;                               \
      __builtin_amdgcn_global_load_lds((const __attribute__((address_space(1))) void*)ks_, \
          (__attribute__((address_space(3))) void*)kb_, 16, 0, 0);                   \
      __builtin_amdgcn_global_load_lds((const __attribute__((address_space(1))) void*)(ks_ + 32*3072), \
          (__attribute__((address_space(3))) void*)(kb_ + 4096), 16, 0, 0);          \
      __builtin_amdgcn_global_load_lds((const __attribute__((address_space(1))) void*)vs_, \
          (__attribute__((address_space(3))) void*)vb_, 16, 0, 0);                   \
      __builtin_amdgcn_global_load_lds((const __attribute__((address_space(1))) void*)(vs_ + 32*2048), \
          (__attribute__((address_space(3))) void*)(vb_ + 4096), 16, 0, 0);          \
    } while (0)

  f32x16 OA[2] = {}, OB[2] = {};
  float lA = 0.f, lB = 0.f;
  const int nktA = 2*tA + 2, nktB = 2*tB + 2;   // nktB == max

  auto process = [&](int kt, const char* kb, const char* vb,
                     const bf16x8 (&qf)[4], f32x16 (&O)[2], float& l,
                     int wq0, int qg){
    const bool domask = (kt*64 + 63 > wq0);
    #pragma unroll
    for (int sub = 0; sub < 2; ++sub){
      f32x16 S = {};
      __builtin_amdgcn_s_setprio(1);
      #pragma unroll
      for (int c4 = 0; c4 < 4; ++c4){
        const bf16x8 kf = *(const bf16x8*)(kb + (sub*32 + q31)*128
                              + ((((c4<<1)|hi) ^ (q31 & 7)) << 4));
        S = __builtin_amdgcn_mfma_f32_32x32x16_bf16(kf, qf[c4], S, 0, 0, 0);
      }
      __builtin_amdgcn_s_setprio(0);
      if (domask){
        #pragma unroll
        for (int r = 0; r < 16; ++r){
          const int kg = kt*64 + sub*32 + (r&3) + 8*(r>>2) + 4*hi;
          if (kg > qg) S[r] = -1e30f;
        }
      }
      float ps = 0.f;
      #pragma unroll
      for (int r = 0; r < 16; ++r){
        S[r] = __builtin_amdgcn_exp2f(S[r]);   // P = 2^(q.k*sc); shift cancels in 1/l
        ps += S[r];
      }
      l += ps;
      bf16x8 paf[2];
      #pragma unroll
      for (int kc = 0; kc < 2; ++kc){
        const int e = kc * 8;
        unsigned int a, bb, cc, dd;
        asm("v_cvt_pk_bf16_f32 %0, %1, %2" : "=v"(a)  : "v"(S[e+0]), "v"(S[e+1]));
        asm("v_cvt_pk_bf16_f32 %0, %1, %2" : "=v"(bb) : "v"(S[e+4]), "v"(S[e+5]));
        asm("v_cvt_pk_bf16_f32 %0, %1, %2" : "=v"(cc) : "v"(S[e+2]), "v"(S[e+3]));
        asm("v_cvt_pk_bf16_f32 %0, %1, %2" : "=v"(dd) : "v"(S[e+6]), "v"(S[e+7]));
        asm volatile("v_permlane32_swap_b32 %0, %1" : "+v"(a),  "+v"(bb));
        asm volatile("v_permlane32_swap_b32 %0, %1" : "+v"(cc), "+v"(dd));
        i32x4 pwv; pwv[0] = (int)a; pwv[1] = (int)cc; pwv[2] = (int)bb; pwv[3] = (int)dd;
        paf[kc] = __builtin_bit_cast(bf16x8, pwv);
      }
      __builtin_amdgcn_s_setprio(1);
      #pragma unroll
      for (int kc = 0; kc < 2; ++kc){
        #pragma unroll
        for (int dblk = 0; dblk < 2; ++dblk){
          const int dr = dblk*32 + q31;
          const bf16x8 vf = *(const bf16x8*)(vb + dr*128
                                + ((((sub<<2)|(kc<<1)|hi) ^ (dr & 7)) << 4));
          O[dblk] = __builtin_amdgcn_mfma_f32_32x32x16_bf16(paf[kc], vf, O[dblk], 0, 0, 0);
        }
      }
      __builtin_amdgcn_s_setprio(0);
    }
  };

  STAGE(0, 0);
  __syncthreads();

  int cbuf = 0;
  for (int kt = 0; kt < nktB; ++kt){
    if (kt + 1 < nktB) STAGE(kt + 1, cbuf ^ 1);
    const char* kb = Ksm[cbuf];
    const char* vb = Vsm[cbuf];
    if (kt*64 <= wq0A + 31) process(kt, kb, vb, qfA, OA, lA, wq0A, qgA);
    if (kt*64 <= wq0B + 31) process(kt, kb, vb, qfB, OB, lB, wq0B, qgB);
    __syncthreads();   // drains global_load_lds + publishes next buffer
    cbuf ^= 1;
  }

  // combine lane-halves' partial l (same q), publish 1/l per q
  {
    const float lcA = lA + __shfl_xor(lA, 32);
    const float lcB = lB + __shfl_xor(lB, 32);
    if (lane < 32){ Ls[0][w][lane] = 1.0f / lcA; Ls[1][w][lane] = 1.0f / lcB; }
  }
  __syncthreads();

  // store both tiles: O row r -> q = wq0 + (r&3)+8*(r>>2)+4*hi ; d = dblk*32+q31
  #pragma unroll
  for (int t = 0; t < 2; ++t){
    const int wq0 = t ? wq0B : wq0A;
    #pragma unroll
    for (int r = 0; r < 16; ++r){
      const int qloc = (r&3) + 8*(r>>2) + 4*hi;
      const float inv = Ls[t][w][qloc];
      const size_t row = rowB + wq0 + qloc;
      #pragma unroll
      for (int dblk = 0; dblk < 2; ++dblk){
        const float ov = t ? OB[dblk][r] : OA[dblk][r];
        y[row * CEMB + h*64 + dblk*32 + q31] = f2bf(ov * inv);
      }
    }
  }
  #undef STAGE
}

extern "C" void kernel_launch(void* const* d_in, const int* in_sizes, int n_in,
                              void* d_out, int out_size, void* d_ws, size_t ws_size,
                              hipStream_t stream)
{
  const float* x     = (const float*)d_in[0];
  const float* w_qkv = (const float*)d_in[1];
  const float* b_qkv = (const float*)d_in[2];
  const float* w_out = (const float*)d_in[3];
  const float* b_out = (const float*)d_in[4];
  float* out = (float*)d_out;

  char* ws = (char*)d_ws;
  unsigned short* xb    = (unsigned short*)(ws);                 // 16 MiB; dead after gemm1
  unsigned short* vTb   = (unsigned short*)(ws);                 // 16 MiB (reuses xb)
  unsigned short* qkvb  = (unsigned short*)(ws + (16u<<20));     // 48 MiB [8192,3072]
  unsigned short* yb    = (unsigned short*)(ws + (64u<<20));     // 16 MiB [8192,1024]
  unsigned short* wqkvT = (unsigned short*)(ws + (80u<<20));     //  6 MiB [3072,1024]
  unsigned short* woutT = (unsigned short*)(ws + (86u<<20));     //  2 MiB [1024,1024]

  const int M = 4 * TSEQ; // 8192

  k_cvt_bf16<<<(M * CEMB / 4 + 255) / 256, 256, 0, stream>>>(x, xb, M * CEMB / 4);
  k_transpose_bf16<<<dim3(3072/32, 1024/32), 256, 0, stream>>>(w_qkv, wqkvT, 1024, 3072);
  k_transpose_bf16<<<dim3(1024/32, 1024/32), 256, 0, stream>>>(w_out, woutT, 1024, 1024);

  k_gemm_bt<true ><<<dim3(3072/128, M/128), 256, 0, stream>>>(xb, wqkvT, b_qkv, qkvb, M, 3072, 1024);
  k_vT<<<dim3(64, TSEQ/64), 256, 0, stream>>>(qkvb, vTb);
  k_attn<<<dim3(4 * 16, 8), 256, 0, stream>>>(qkvb, vTb, yb);
  k_gemm_bt<false><<<dim3(1024/128, M/128), 256, 0, stream>>>(yb, woutT, b_out, out, M, 1024, 1024);
}

// Round 6
// 177.565 us; speedup vs baseline: 1.2400x; 1.2400x over previous
//
#include <hip/hip_runtime.h>
#include <hip/hip_bf16.h>

#define TSEQ 2048
#define CEMB 1024

typedef __attribute__((ext_vector_type(8))) short bf16x8;
typedef __attribute__((ext_vector_type(4))) float f32x4;
typedef __attribute__((ext_vector_type(16))) float f32x16;
typedef __attribute__((ext_vector_type(4))) int i32x4;

__device__ __forceinline__ unsigned short f2bf(float f){
  return __builtin_bit_cast(unsigned short, __float2bfloat16(f));
}

// ---------- f32 -> bf16 elementwise (4 elems/thread) ----------
__global__ void k_cvt_bf16(const float* __restrict__ in, unsigned short* __restrict__ out, int n4){
  int i = blockIdx.x * blockDim.x + threadIdx.x;
  if (i >= n4) return;
  const float4 v = reinterpret_cast<const float4*>(in)[i];
  ushort4 o;
  o.x = f2bf(v.x); o.y = f2bf(v.y); o.z = f2bf(v.z); o.w = f2bf(v.w);
  reinterpret_cast<ushort4*>(out)[i] = o;
}

// ---------- transpose + convert: w [K,N] f32 -> wT [N,K] bf16 ----------
__global__ void k_transpose_bf16(const float* __restrict__ w, unsigned short* __restrict__ wT, int K, int N){
  __shared__ unsigned short tile[32][33];
  const int n0 = blockIdx.x * 32, k0 = blockIdx.y * 32;
  const int tx = threadIdx.x & 31, ty = threadIdx.x >> 5; // ty 0..7
  #pragma unroll
  for (int r = 0; r < 4; ++r){
    int k = ty * 4 + r;
    tile[k][tx] = f2bf(w[(size_t)(k0 + k) * N + n0 + tx]);
  }
  __syncthreads();
  #pragma unroll
  for (int r = 0; r < 4; ++r){
    int n = ty * 4 + r;
    wT[(size_t)(n0 + n) * K + k0 + tx] = tile[tx][n];
  }
}

// ---------- V head-transpose: qkv[t][2048+h*64+d] -> vT[(bh*64+d)][t] ----------
__global__ __launch_bounds__(256) void k_vT(const unsigned short* __restrict__ qkv,
                                            unsigned short* __restrict__ vT){
  __shared__ __align__(16) unsigned short tile[64*64];
  const int tid = threadIdx.x;
  const int bh = blockIdx.x;          // b*16+h
  const int t0 = blockIdx.y * 64;
  const int b = bh >> 4, h = bh & 15;
  const int lt = tid >> 3, seg = tid & 7;
  #pragma unroll
  for (int r = 0; r < 2; ++r){
    const int t = lt + 32*r;
    const i32x4 v = *(const i32x4*)&qkv[((size_t)(b*TSEQ + t0 + t))*3072 + 2048 + h*64 + seg*8];
    const int slot = seg ^ (t & 7) ^ (t >> 3);
    *(i32x4*)((char*)tile + t*128 + slot*16) = v;
  }
  __syncthreads();
  const int w = tid >> 6, lane = tid & 63;
  const int tseg = lane & 7;
  #pragma unroll
  for (int r = 0; r < 2; ++r){
    const int d = w*8 + (lane>>3) + 32*r;
    unsigned int wd[4];
    #pragma unroll
    for (int jp = 0; jp < 4; ++jp){
      unsigned int lo, hi;
      #pragma unroll
      for (int e = 0; e < 2; ++e){
        const int j = jp*2 + e;
        const int t = tseg*8 + j;
        const int byteoff = t*128 + ((2*d) ^ (((j ^ tseg) & 7) << 4));
        const unsigned int val = *(const unsigned short*)((const char*)tile + byteoff);
        if (e == 0) lo = val; else hi = val;
      }
      wd[jp] = lo | (hi << 16);
    }
    i32x4 o4; o4[0]=wd[0]; o4[1]=wd[1]; o4[2]=wd[2]; o4[3]=wd[3];
    *(i32x4*)&vT[((size_t)bh*64 + d)*2048 + t0 + tseg*8] = o4;
  }
}

// ---------- GEMM: C[M,N] = A[M,K](bf16) * Bt[N,K](bf16)^T + bias ----------
// m97 structure + T1 bijective XCD swizzle (m204).
template<bool OUT_BF16>
__global__ __launch_bounds__(256) void k_gemm_bt(
    const unsigned short* __restrict__ A,
    const unsigned short* __restrict__ Bt,
    const float* __restrict__ bias,
    void* __restrict__ Cout, int M, int N, int K)
{
  __shared__ __align__(16) unsigned short As[128*32];
  __shared__ __align__(16) unsigned short Bs[128*32];
  const int tid = threadIdx.x;
  const int lane = tid & 63, w = tid >> 6;
  const int wr = w >> 1, wc = w & 1;
  const int l15 = lane & 15, l4 = lane >> 4;

  // T1: bijective XCD-aware remap of the flattened block id
  const unsigned nwg = gridDim.x * gridDim.y;
  unsigned lin = blockIdx.y * gridDim.x + blockIdx.x;
  {
    const unsigned qq = nwg >> 3, rr = nwg & 7;
    const unsigned xcd = lin & 7, loc = lin >> 3;
    lin = (xcd < rr ? xcd * (qq + 1) : rr * (qq + 1) + (xcd - rr) * qq) + loc;
  }
  const int m0 = (int)(lin / gridDim.x) * 128;
  const int n0 = (int)(lin % gridDim.x) * 128;

  const unsigned short* Ag = A + (size_t)(m0 + (tid >> 2)) * K + (tid & 3) * 8;
  const unsigned short* Bg = Bt + (size_t)(n0 + (tid >> 2)) * K + (tid & 3) * 8;

  f32x4 acc[4][4] = {};

  for (int kk = 0; kk < K; kk += 32){
    #pragma unroll
    for (int rd = 0; rd < 2; ++rd){
      __builtin_amdgcn_global_load_lds(
        (const __attribute__((address_space(1))) void*)(Ag + kk + (size_t)rd * 64 * K),
        (__attribute__((address_space(3))) void*)&As[(rd * 256 + w * 64) * 8],
        16, 0, 0);
      __builtin_amdgcn_global_load_lds(
        (const __attribute__((address_space(1))) void*)(Bg + kk + (size_t)rd * 64 * K),
        (__attribute__((address_space(3))) void*)&Bs[(rd * 256 + w * 64) * 8],
        16, 0, 0);
    }
    __syncthreads();
    bf16x8 af[4], bfr[4];
    #pragma unroll
    for (int m = 0; m < 4; ++m)
      af[m] = *(const bf16x8*)&As[(wr*64 + m*16 + l15) * 32 + l4*8];
    #pragma unroll
    for (int n = 0; n < 4; ++n)
      bfr[n] = *(const bf16x8*)&Bs[(wc*64 + n*16 + l15) * 32 + l4*8];
    #pragma unroll
    for (int m = 0; m < 4; ++m){
      #pragma unroll
      for (int n = 0; n < 4; ++n)
        acc[m][n] = __builtin_amdgcn_mfma_f32_16x16x32_bf16(af[m], bfr[n], acc[m][n], 0, 0, 0);
    }
    __syncthreads();
  }

  float bv[4];
  #pragma unroll
  for (int n = 0; n < 4; ++n) bv[n] = bias[n0 + wc*64 + n*16 + l15];

  #pragma unroll
  for (int m = 0; m < 4; ++m){
    const int row = m0 + wr*64 + m*16 + l4*4;
    #pragma unroll
    for (int n = 0; n < 4; ++n){
      const int col = n0 + wc*64 + n*16 + l15;
      #pragma unroll
      for (int r = 0; r < 4; ++r){
        float v = acc[m][n][r] + bv[n];
        if (OUT_BF16)
          ((unsigned short*)Cout)[(size_t)(row + r) * N + col] = f2bf(v);
        else
          ((float*)Cout)[(size_t)(row + r) * N + col] = v;
      }
    }
  }
}

// ---------- causal flash attention v6 ----------
// Folded-diagonal pairing with 8 waves/block (512 thr): wavegroup 0 (waves
// 0-3) owns q-tile p, wavegroup 1 (waves 4-7) owns q-tile 15-p; K/V staging
// SHARED by both groups. Every block has identical total work (no tail);
// per-thread state is single-tile (VGPR ~ v4 level). Swapped QK^T (32x32x16),
// in-register softmax (Q pre-scaled, shift-free), T12 cvt_pk+permlane pack,
// direct global_load_lds double-buffer, ONE barrier per 64-key tile.
__global__ __launch_bounds__(512, 4) void k_attn(
    const unsigned short* __restrict__ qkv,
    const unsigned short* __restrict__ vT,
    unsigned short* __restrict__ y)
{
  __shared__ __align__(16) char Ksm[2][8192];   // [key 64][128B], slot^=(key&7)
  __shared__ __align__(16) char Vsm[2][8192];   // [d 64][128B],  slot^=(d&7)
  __shared__ float Ls[8][32];

  const int tid = threadIdx.x, lane = tid & 63, w = tid >> 6;  // w 0..7
  const int q31 = lane & 31, hi = lane >> 5;
  const int bh = blockIdx.x, p = blockIdx.y;    // p in [0,8)
  const int g = w >> 2, wl = w & 3;
  const int myt = g ? (15 - p) : p;             // this wavegroup's q-tile
  const int b = bh >> 4, h = bh & 15;
  const size_t rowB = (size_t)b * TSEQ;

  const int wq0 = myt*128 + 32*wl, qg = wq0 + q31;
  const int nkt_my = 2*myt + 2;
  const int nktB  = 2*(15 - p) + 2;             // loop bound (B is the heavy tile)

  const float sc = 0.18033688011112042f;   // (1/sqrt(64)) * log2(e)

  // hoisted Q as B-fragments, PRE-SCALED by sc
  bf16x8 qf[4];
  {
    const unsigned short* qp = qkv + (rowB + qg) * 3072 + h * 64;
    #pragma unroll
    for (int c4 = 0; c4 < 4; ++c4){
      bf16x8 v = *(const bf16x8*)(qp + c4*16 + hi*8);
      #pragma unroll
      for (int j = 0; j < 8; ++j){
        const unsigned int bits = ((unsigned int)(unsigned short)v[j]) << 16;
        v[j] = (short)f2bf(__builtin_bit_cast(float, bits) * sc);
      }
      qf[c4] = v;
    }
  }

  // staging geometry: 512 thr cover 64 rows x 8 chunks exactly once.
  // wave w covers rows w*8 .. w*8+7; slot sl, content-chunk cx = sl ^ (row&7)
  const int kr = lane >> 3, sl = lane & 7, cx = sl ^ kr;
  const unsigned short* kgbase = qkv + (rowB + w*8 + kr) * 3072 + 1024 + h*64 + cx*8;
  const unsigned short* vgbase = vT + ((size_t)bh*64 + w*8 + kr) * 2048 + cx*8;

  #define STAGE(ktile, buf)                                                          \
    do {                                                                             \
      __builtin_amdgcn_global_load_lds(                                              \
        (const __attribute__((address_space(1))) void*)(kgbase + (size_t)(ktile)*64*3072), \
        (__attribute__((address_space(3))) void*)(&Ksm[buf][0] + w*1024), 16, 0, 0); \
      __builtin_amdgcn_global_load_lds(                                              \
        (const __attribute__((address_space(1))) void*)(vgbase + (ktile)*64),        \
        (__attribute__((address_space(3))) void*)(&Vsm[buf][0] + w*1024), 16, 0, 0); \
    } while (0)

  f32x16 O[2] = {};
  float l = 0.f;

  STAGE(0, 0);
  __syncthreads();

  int cbuf = 0;
  for (int kt = 0; kt < nktB; ++kt){
    if (kt + 1 < nktB) STAGE(kt + 1, cbuf ^ 1);

    if (kt < nkt_my){
      const char* kb = Ksm[cbuf];
      const char* vb = Vsm[cbuf];
      const bool domask = (kt*64 + 63 > wq0);
      #pragma unroll
      for (int sub = 0; sub < 2; ++sub){
        f32x16 S = {};
        __builtin_amdgcn_s_setprio(1);
        #pragma unroll
        for (int c4 = 0; c4 < 4; ++c4){
          const bf16x8 kf = *(const bf16x8*)(kb + (sub*32 + q31)*128
                                + ((((c4<<1)|hi) ^ (q31 & 7)) << 4));
          S = __builtin_amdgcn_mfma_f32_32x32x16_bf16(kf, qf[c4], S, 0, 0, 0);
        }
        __builtin_amdgcn_s_setprio(0);
        if (domask){
          #pragma unroll
          for (int r = 0; r < 16; ++r){
            const int kg = kt*64 + sub*32 + (r&3) + 8*(r>>2) + 4*hi;
            if (kg > qg) S[r] = -1e30f;
          }
        }
        float ps = 0.f;
        #pragma unroll
        for (int r = 0; r < 16; ++r){
          S[r] = __builtin_amdgcn_exp2f(S[r]);   // shift-free; cancels in 1/l
          ps += S[r];
        }
        l += ps;
        bf16x8 paf[2];
        #pragma unroll
        for (int kc = 0; kc < 2; ++kc){
          const int e = kc * 8;
          unsigned int a, bb, cc, dd;
          asm("v_cvt_pk_bf16_f32 %0, %1, %2" : "=v"(a)  : "v"(S[e+0]), "v"(S[e+1]));
          asm("v_cvt_pk_bf16_f32 %0, %1, %2" : "=v"(bb) : "v"(S[e+4]), "v"(S[e+5]));
          asm("v_cvt_pk_bf16_f32 %0, %1, %2" : "=v"(cc) : "v"(S[e+2]), "v"(S[e+3]));
          asm("v_cvt_pk_bf16_f32 %0, %1, %2" : "=v"(dd) : "v"(S[e+6]), "v"(S[e+7]));
          asm volatile("v_permlane32_swap_b32 %0, %1" : "+v"(a),  "+v"(bb));
          asm volatile("v_permlane32_swap_b32 %0, %1" : "+v"(cc), "+v"(dd));
          i32x4 pwv; pwv[0] = (int)a; pwv[1] = (int)cc; pwv[2] = (int)bb; pwv[3] = (int)dd;
          paf[kc] = __builtin_bit_cast(bf16x8, pwv);
        }
        __builtin_amdgcn_s_setprio(1);
        #pragma unroll
        for (int kc = 0; kc < 2; ++kc){
          #pragma unroll
          for (int dblk = 0; dblk < 2; ++dblk){
            const int dr = dblk*32 + q31;
            const bf16x8 vf = *(const bf16x8*)(vb + dr*128
                                  + ((((sub<<2)|(kc<<1)|hi) ^ (dr & 7)) << 4));
            O[dblk] = __builtin_amdgcn_mfma_f32_32x32x16_bf16(paf[kc], vf, O[dblk], 0, 0, 0);
          }
        }
        __builtin_amdgcn_s_setprio(0);
      }
    }

    __syncthreads();   // drains global_load_lds + publishes next buffer
    cbuf ^= 1;
  }

  // combine lane-halves' partial l (same q), publish 1/l per q (wave-private row)
  {
    const float lc = l + __shfl_xor(l, 32);
    if (lane < 32) Ls[w][lane] = 1.0f / lc;
  }
  __syncthreads();

  // store: O row r -> q = wq0 + (r&3)+8*(r>>2)+4*hi ; d = dblk*32+q31
  #pragma unroll
  for (int r = 0; r < 16; ++r){
    const int qloc = (r&3) + 8*(r>>2) + 4*hi;
    const float inv = Ls[w][qloc];
    const size_t row = rowB + wq0 + qloc;
    #pragma unroll
    for (int dblk = 0; dblk < 2; ++dblk)
      y[row * CEMB + h*64 + dblk*32 + q31] = f2bf(O[dblk][r] * inv);
  }
  #undef STAGE
}

extern "C" void kernel_launch(void* const* d_in, const int* in_sizes, int n_in,
                              void* d_out, int out_size, void* d_ws, size_t ws_size,
                              hipStream_t stream)
{
  const float* x     = (const float*)d_in[0];
  const float* w_qkv = (const float*)d_in[1];
  const float* b_qkv = (const float*)d_in[2];
  const float* w_out = (const float*)d_in[3];
  const float* b_out = (const float*)d_in[4];
  float* out = (float*)d_out;

  char* ws = (char*)d_ws;
  unsigned short* xb    = (unsigned short*)(ws);                 // 16 MiB; dead after gemm1
  unsigned short* vTb   = (unsigned short*)(ws);                 // 16 MiB (reuses xb)
  unsigned short* qkvb  = (unsigned short*)(ws + (16u<<20));     // 48 MiB [8192,3072]
  unsigned short* yb    = (unsigned short*)(ws + (64u<<20));     // 16 MiB [8192,1024]
  unsigned short* wqkvT = (unsigned short*)(ws + (80u<<20));     //  6 MiB [3072,1024]
  unsigned short* woutT = (unsigned short*)(ws + (86u<<20));     //  2 MiB [1024,1024]

  const int M = 4 * TSEQ; // 8192

  k_cvt_bf16<<<(M * CEMB / 4 + 255) / 256, 256, 0, stream>>>(x, xb, M * CEMB / 4);
  k_transpose_bf16<<<dim3(3072/32, 1024/32), 256, 0, stream>>>(w_qkv, wqkvT, 1024, 3072);
  k_transpose_bf16<<<dim3(1024/32, 1024/32), 256, 0, stream>>>(w_out, woutT, 1024, 1024);

  k_gemm_bt<true ><<<dim3(3072/128, M/128), 256, 0, stream>>>(xb, wqkvT, b_qkv, qkvb, M, 3072, 1024);
  k_vT<<<dim3(64, TSEQ/64), 256, 0, stream>>>(qkvb, vTb);
  k_attn<<<dim3(4 * 16, 8), 512, 0, stream>>>(qkvb, vTb, yb);
  k_gemm_bt<false><<<dim3(1024/128, M/128), 256, 0, stream>>>(yb, woutT, b_out, out, M, 1024, 1024);
}

// Round 7
// 167.216 us; speedup vs baseline: 1.3167x; 1.0619x over previous
//
#include <hip/hip_runtime.h>
#include <hip/hip_bf16.h>

#define TSEQ 2048
#define CEMB 1024

typedef __attribute__((ext_vector_type(8))) short bf16x8;
typedef __attribute__((ext_vector_type(4))) float f32x4;
typedef __attribute__((ext_vector_type(16))) float f32x16;
typedef __attribute__((ext_vector_type(4))) int i32x4;

__device__ __forceinline__ unsigned short f2bf(float f){
  return __builtin_bit_cast(unsigned short, __float2bfloat16(f));
}

__device__ __forceinline__ f32x4 MFMA16(bf16x8 a, bf16x8 b, f32x4 c){
  return __builtin_amdgcn_mfma_f32_16x16x32_bf16(a, b, c, 0, 0, 0);
}

#define GLDS(src, dst) __builtin_amdgcn_global_load_lds( \
      (const __attribute__((address_space(1))) void*)(src), \
      (__attribute__((address_space(3))) void*)(dst), 16, 0, 0)

// ---------- f32 -> bf16 elementwise (4 elems/thread) ----------
__global__ void k_cvt_bf16(const float* __restrict__ in, unsigned short* __restrict__ out, int n4){
  int i = blockIdx.x * blockDim.x + threadIdx.x;
  if (i >= n4) return;
  const float4 v = reinterpret_cast<const float4*>(in)[i];
  ushort4 o;
  o.x = f2bf(v.x); o.y = f2bf(v.y); o.z = f2bf(v.z); o.w = f2bf(v.w);
  reinterpret_cast<ushort4*>(out)[i] = o;
}

// ---------- transpose + convert: w [K,N] f32 -> wT [N,K] bf16 ----------
__global__ void k_transpose_bf16(const float* __restrict__ w, unsigned short* __restrict__ wT, int K, int N){
  __shared__ unsigned short tile[32][33];
  const int n0 = blockIdx.x * 32, k0 = blockIdx.y * 32;
  const int tx = threadIdx.x & 31, ty = threadIdx.x >> 5; // ty 0..7
  #pragma unroll
  for (int r = 0; r < 4; ++r){
    int k = ty * 4 + r;
    tile[k][tx] = f2bf(w[(size_t)(k0 + k) * N + n0 + tx]);
  }
  __syncthreads();
  #pragma unroll
  for (int r = 0; r < 4; ++r){
    int n = ty * 4 + r;
    wT[(size_t)(n0 + n) * K + k0 + tx] = tile[tx][n];
  }
}

// ---------- V head-transpose: qkv[t][2048+h*64+d] -> vT[(bh*64+d)][t] ----------
__global__ __launch_bounds__(256) void k_vT(const unsigned short* __restrict__ qkv,
                                            unsigned short* __restrict__ vT){
  __shared__ __align__(16) unsigned short tile[64*64];
  const int tid = threadIdx.x;
  const int bh = blockIdx.x;          // b*16+h
  const int t0 = blockIdx.y * 64;
  const int b = bh >> 4, h = bh & 15;
  const int lt = tid >> 3, seg = tid & 7;
  #pragma unroll
  for (int r = 0; r < 2; ++r){
    const int t = lt + 32*r;
    const i32x4 v = *(const i32x4*)&qkv[((size_t)(b*TSEQ + t0 + t))*3072 + 2048 + h*64 + seg*8];
    const int slot = seg ^ (t & 7) ^ (t >> 3);
    *(i32x4*)((char*)tile + t*128 + slot*16) = v;
  }
  __syncthreads();
  const int w = tid >> 6, lane = tid & 63;
  const int tseg = lane & 7;
  #pragma unroll
  for (int r = 0; r < 2; ++r){
    const int d = w*8 + (lane>>3) + 32*r;
    unsigned int wd[4];
    #pragma unroll
    for (int jp = 0; jp < 4; ++jp){
      unsigned int lo, hi;
      #pragma unroll
      for (int e = 0; e < 2; ++e){
        const int j = jp*2 + e;
        const int t = tseg*8 + j;
        const int byteoff = t*128 + ((2*d) ^ (((j ^ tseg) & 7) << 4));
        const unsigned int val = *(const unsigned short*)((const char*)tile + byteoff);
        if (e == 0) lo = val; else hi = val;
      }
      wd[jp] = lo | (hi << 16);
    }
    i32x4 o4; o4[0]=wd[0]; o4[1]=wd[1]; o4[2]=wd[2]; o4[3]=wd[3];
    *(i32x4*)&vT[((size_t)bh*64 + d)*2048 + t0 + tseg*8] = o4;
  }
}

// ---------- GEMM 128x128 (m97 structure) — used for the out-projection ----------
template<bool OUT_BF16>
__global__ __launch_bounds__(256) void k_gemm_bt(
    const unsigned short* __restrict__ A,
    const unsigned short* __restrict__ Bt,
    const float* __restrict__ bias,
    void* __restrict__ Cout, int M, int N, int K)
{
  __shared__ __align__(16) unsigned short As[128*32];
  __shared__ __align__(16) unsigned short Bs[128*32];
  const int tid = threadIdx.x;
  const int lane = tid & 63, w = tid >> 6;
  const int wr = w >> 1, wc = w & 1;
  const int l15 = lane & 15, l4 = lane >> 4;

  const unsigned nwg = gridDim.x * gridDim.y;
  unsigned lin = blockIdx.y * gridDim.x + blockIdx.x;
  {
    const unsigned qq = nwg >> 3, rr = nwg & 7;
    const unsigned xcd = lin & 7, loc = lin >> 3;
    lin = (xcd < rr ? xcd * (qq + 1) : rr * (qq + 1) + (xcd - rr) * qq) + loc;
  }
  const int m0 = (int)(lin / gridDim.x) * 128;
  const int n0 = (int)(lin % gridDim.x) * 128;

  const unsigned short* Ag = A + (size_t)(m0 + (tid >> 2)) * K + (tid & 3) * 8;
  const unsigned short* Bg = Bt + (size_t)(n0 + (tid >> 2)) * K + (tid & 3) * 8;

  f32x4 acc[4][4] = {};

  for (int kk = 0; kk < K; kk += 32){
    #pragma unroll
    for (int rd = 0; rd < 2; ++rd){
      GLDS(Ag + kk + (size_t)rd * 64 * K, &As[(rd * 256 + w * 64) * 8]);
      GLDS(Bg + kk + (size_t)rd * 64 * K, &Bs[(rd * 256 + w * 64) * 8]);
    }
    __syncthreads();
    bf16x8 af[4], bfr[4];
    #pragma unroll
    for (int m = 0; m < 4; ++m)
      af[m] = *(const bf16x8*)&As[(wr*64 + m*16 + l15) * 32 + l4*8];
    #pragma unroll
    for (int n = 0; n < 4; ++n)
      bfr[n] = *(const bf16x8*)&Bs[(wc*64 + n*16 + l15) * 32 + l4*8];
    #pragma unroll
    for (int m = 0; m < 4; ++m){
      #pragma unroll
      for (int n = 0; n < 4; ++n)
        acc[m][n] = MFMA16(af[m], bfr[n], acc[m][n]);
    }
    __syncthreads();
  }

  float bv[4];
  #pragma unroll
  for (int n = 0; n < 4; ++n) bv[n] = bias[n0 + wc*64 + n*16 + l15];

  #pragma unroll
  for (int m = 0; m < 4; ++m){
    const int row = m0 + wr*64 + m*16 + l4*4;
    #pragma unroll
    for (int n = 0; n < 4; ++n){
      const int col = n0 + wc*64 + n*16 + l15;
      #pragma unroll
      for (int r = 0; r < 4; ++r){
        float v = acc[m][n][r] + bv[n];
        if (OUT_BF16)
          ((unsigned short*)Cout)[(size_t)(row + r) * N + col] = f2bf(v);
        else
          ((float*)Cout)[(size_t)(row + r) * N + col] = v;
      }
    }
  }
}

// ---------- GEMM 256x256 deep-pipelined (T2+T3+T4+T5) — QKV projection ----------
// 512 thr = 8 waves (2M x 4N); per-wave 128x64 output (acc[8][4]); BK=64,
// two K-tiles in flight (buf0/buf1), raw s_barrier + counted vmcnt(8) —
// loads NEVER drain in the main loop. LDS content swizzle: chunk ^= row&7,
// applied on the global SOURCE (linear global_load_lds dest) and on reads.
template<bool OUT_BF16>
__global__ __launch_bounds__(512, 2) void k_gemm256(
    const unsigned short* __restrict__ A,
    const unsigned short* __restrict__ Bt,
    const float* __restrict__ bias,
    void* __restrict__ Cout, int M, int N, int K)
{
  __shared__ __align__(16) char smem[131072];  // A:[2][32K] @0, B:[2][32K] @64K
  const int tid = threadIdx.x;
  const int lane = tid & 63, w = tid >> 6;      // 8 waves
  const int wm = w >> 2, wn = w & 3;
  const int l15 = lane & 15, l4 = lane >> 4;
  const int x7 = l15 & 7;

  // T1 bijective XCD swizzle (grid % 8 == 0)
  unsigned lin = blockIdx.x;
  {
    const unsigned nwg = gridDim.x;
    const unsigned qq = nwg >> 3, rr = nwg & 7;
    const unsigned xcd = lin & 7, loc = lin >> 3;
    lin = (xcd < rr ? xcd * (qq + 1) : rr * (qq + 1) + (xcd - rr) * qq) + loc;
  }
  const unsigned ntn = (unsigned)N >> 8;
  const int m0 = (int)(lin / ntn) << 8;
  const int n0 = (int)(lin % ntn) << 8;

  // staging: 4 gload_lds per (tile, matrix); inst i covers rows i*64..+63.
  // wave w writes rows w*8..w*8+7 of each inst group; source chunk pre-swizzled.
  const int srow = lane >> 3;                  // 0..7
  const int scx  = (lane & 7) ^ srow;          // content chunk (involution)
  const unsigned short* Ag = A  + (size_t)(m0 + w*8 + srow) * K + scx * 8;
  const unsigned short* Bg = Bt + (size_t)(n0 + w*8 + srow) * K + scx * 8;
  char* const As0 = smem + (w << 10);
  char* const Bs0 = smem + 65536 + (w << 10);

  auto stageA = [&](int buf, int kt){
    const unsigned short* s = Ag + kt*64;
    char* d = As0 + buf*32768;
    #pragma unroll
    for (int i = 0; i < 4; ++i) GLDS(s + (size_t)(i*64)*K, d + i*8192);
  };
  auto stageB = [&](int buf, int kt){
    const unsigned short* s = Bg + kt*64;
    char* d = Bs0 + buf*32768;
    #pragma unroll
    for (int i = 0; i < 4; ++i) GLDS(s + (size_t)(i*64)*K, d + i*8192);
  };

  // frag reads: row*128 B + ((chunk ^ (row&7))*16); row&7 == l15&7 == x7
  const int arow = wm*128 + l15;
  const int brow = wn*64  + l15;
  auto rdA = [&](int buf, int m, int ks)->bf16x8 {
    return *(const bf16x8*)(smem + buf*32768 + (arow + m*16)*128 + (((ks*4 + l4) ^ x7) << 4));
  };
  auto rdB = [&](int buf, int n, int ks)->bf16x8 {
    return *(const bf16x8*)(smem + 65536 + buf*32768 + (brow + n*16)*128 + (((ks*4 + l4) ^ x7) << 4));
  };

  f32x4 acc[8][4] = {};
  const int NIT = K >> 7;                      // iterations over 2 K-tiles

  stageA(0, 0); stageB(0, 0);                  // 8 loads (tile 0)
  stageA(1, 1); stageB(1, 1);                  // 8 loads (tile 1)
  asm volatile("s_waitcnt vmcnt(8)" ::: "memory");   // tile 0 landed
  __builtin_amdgcn_s_barrier();
  asm volatile("" ::: "memory");

  for (int it = 0; it < NIT; ++it){
    const bool more = (it + 1 < NIT);
    #pragma unroll
    for (int half = 0; half < 2; ++half){      // K-tile 2it+half lives in buf=half
      const int buf = half;
      bf16x8 bfr[4][2], af1[4][2], af2[4][2];
      // P1: read all B-frags + A-frags m0..3; compute quadrant (m0-3, n0-1)
      #pragma unroll
      for (int n = 0; n < 4; ++n){ bfr[n][0] = rdB(buf, n, 0); bfr[n][1] = rdB(buf, n, 1); }
      #pragma unroll
      for (int m = 0; m < 4; ++m){ af1[m][0] = rdA(buf, m, 0); af1[m][1] = rdA(buf, m, 1); }
      __builtin_amdgcn_s_setprio(1);
      #pragma unroll
      for (int m = 0; m < 4; ++m)
        #pragma unroll
        for (int n = 0; n < 2; ++n)
          #pragma unroll
          for (int ks = 0; ks < 2; ++ks)
            acc[m][n] = MFMA16(af1[m][ks], bfr[n][ks], acc[m][n]);
      __builtin_amdgcn_s_setprio(0);
      // P2: read A-frags m4..7; compute quadrant (m0-3, n2-3)
      #pragma unroll
      for (int m = 0; m < 4; ++m){ af2[m][0] = rdA(buf, m+4, 0); af2[m][1] = rdA(buf, m+4, 1); }
      __builtin_amdgcn_s_setprio(1);
      #pragma unroll
      for (int m = 0; m < 4; ++m)
        #pragma unroll
        for (int n = 2; n < 4; ++n)
          #pragma unroll
          for (int ks = 0; ks < 2; ++ks)
            acc[m][n] = MFMA16(af1[m][ks], bfr[n][ks], acc[m][n]);
      __builtin_amdgcn_s_setprio(0);
      // P3: compute quadrant (m4-7, n2-3); then drain LDS reads & barrier
      __builtin_amdgcn_s_setprio(1);
      #pragma unroll
      for (int m = 0; m < 4; ++m)
        #pragma unroll
        for (int n = 2; n < 4; ++n)
          #pragma unroll
          for (int ks = 0; ks < 2; ++ks)
            acc[m+4][n] = MFMA16(af2[m][ks], bfr[n][ks], acc[m+4][n]);
      __builtin_amdgcn_s_setprio(0);
      asm volatile("s_waitcnt lgkmcnt(0)" ::: "memory");  // reads physically done
      __builtin_amdgcn_s_barrier();                        // all waves done w/ buf
      asm volatile("" ::: "memory");
      // P4: stage tile (2it+half+2) into this buf; compute quadrant (m4-7, n0-1)
      if (more){ stageA(buf, 2*it + half + 2); stageB(buf, 2*it + half + 2); }
      __builtin_amdgcn_s_setprio(1);
      #pragma unroll
      for (int m = 0; m < 4; ++m)
        #pragma unroll
        for (int n = 0; n < 2; ++n)
          #pragma unroll
          for (int ks = 0; ks < 2; ++ks)
            acc[m+4][n] = MFMA16(af2[m][ks], bfr[n][ks], acc[m+4][n]);
      __builtin_amdgcn_s_setprio(0);
      if (more) asm volatile("s_waitcnt vmcnt(8)" ::: "memory");  // next tile ready
      else      asm volatile("s_waitcnt vmcnt(0)" ::: "memory");
      __builtin_amdgcn_s_barrier();
      asm volatile("" ::: "memory");
    }
  }

  float bv[4];
  #pragma unroll
  for (int n = 0; n < 4; ++n) bv[n] = bias[n0 + wn*64 + n*16 + l15];

  #pragma unroll
  for (int m = 0; m < 8; ++m){
    const int row = m0 + wm*128 + m*16 + l4*4;
    #pragma unroll
    for (int n = 0; n < 4; ++n){
      const int col = n0 + wn*64 + n*16 + l15;
      #pragma unroll
      for (int r = 0; r < 4; ++r){
        float v = acc[m][n][r] + bv[n];
        if (OUT_BF16)
          ((unsigned short*)Cout)[(size_t)(row + r) * N + col] = f2bf(v);
        else
          ((float*)Cout)[(size_t)(row + r) * N + col] = v;
      }
    }
  }
}

// ---------- causal flash attention v6 (unchanged from round 6) ----------
__global__ __launch_bounds__(512, 4) void k_attn(
    const unsigned short* __restrict__ qkv,
    const unsigned short* __restrict__ vT,
    unsigned short* __restrict__ y)
{
  __shared__ __align__(16) char Ksm[2][8192];   // [key 64][128B], slot^=(key&7)
  __shared__ __align__(16) char Vsm[2][8192];   // [d 64][128B],  slot^=(d&7)
  __shared__ float Ls[8][32];

  const int tid = threadIdx.x, lane = tid & 63, w = tid >> 6;  // w 0..7
  const int q31 = lane & 31, hi = lane >> 5;
  const int bh = blockIdx.x, p = blockIdx.y;    // p in [0,8)
  const int g = w >> 2, wl = w & 3;
  const int myt = g ? (15 - p) : p;             // this wavegroup's q-tile
  const int b = bh >> 4, h = bh & 15;
  const size_t rowB = (size_t)b * TSEQ;

  const int wq0 = myt*128 + 32*wl, qg = wq0 + q31;
  const int nkt_my = 2*myt + 2;
  const int nktB  = 2*(15 - p) + 2;

  const float sc = 0.18033688011112042f;   // (1/sqrt(64)) * log2(e)

  bf16x8 qf[4];
  {
    const unsigned short* qp = qkv + (rowB + qg) * 3072 + h * 64;
    #pragma unroll
    for (int c4 = 0; c4 < 4; ++c4){
      bf16x8 v = *(const bf16x8*)(qp + c4*16 + hi*8);
      #pragma unroll
      for (int j = 0; j < 8; ++j){
        const unsigned int bits = ((unsigned int)(unsigned short)v[j]) << 16;
        v[j] = (short)f2bf(__builtin_bit_cast(float, bits) * sc);
      }
      qf[c4] = v;
    }
  }

  const int kr = lane >> 3, sl = lane & 7, cx = sl ^ kr;
  const unsigned short* kgbase = qkv + (rowB + w*8 + kr) * 3072 + 1024 + h*64 + cx*8;
  const unsigned short* vgbase = vT + ((size_t)bh*64 + w*8 + kr) * 2048 + cx*8;

  #define STAGE(ktile, buf)                                                          \
    do {                                                                             \
      GLDS(kgbase + (size_t)(ktile)*64*3072, &Ksm[buf][0] + w*1024);                 \
      GLDS(vgbase + (ktile)*64,              &Vsm[buf][0] + w*1024);                 \
    } while (0)

  f32x16 O[2] = {};
  float l = 0.f;

  STAGE(0, 0);
  __syncthreads();

  int cbuf = 0;
  for (int kt = 0; kt < nktB; ++kt){
    if (kt + 1 < nktB) STAGE(kt + 1, cbuf ^ 1);

    if (kt < nkt_my){
      const char* kb = Ksm[cbuf];
      const char* vb = Vsm[cbuf];
      const bool domask = (kt*64 + 63 > wq0);
      #pragma unroll
      for (int sub = 0; sub < 2; ++sub){
        f32x16 S = {};
        __builtin_amdgcn_s_setprio(1);
        #pragma unroll
        for (int c4 = 0; c4 < 4; ++c4){
          const bf16x8 kf = *(const bf16x8*)(kb + (sub*32 + q31)*128
                                + ((((c4<<1)|hi) ^ (q31 & 7)) << 4));
          S = __builtin_amdgcn_mfma_f32_32x32x16_bf16(kf, qf[c4], S, 0, 0, 0);
        }
        __builtin_amdgcn_s_setprio(0);
        if (domask){
          #pragma unroll
          for (int r = 0; r < 16; ++r){
            const int kg = kt*64 + sub*32 + (r&3) + 8*(r>>2) + 4*hi;
            if (kg > qg) S[r] = -1e30f;
          }
        }
        float ps = 0.f;
        #pragma unroll
        for (int r = 0; r < 16; ++r){
          S[r] = __builtin_amdgcn_exp2f(S[r]);
          ps += S[r];
        }
        l += ps;
        bf16x8 paf[2];
        #pragma unroll
        for (int kc = 0; kc < 2; ++kc){
          const int e = kc * 8;
          unsigned int a, bb, cc, dd;
          asm("v_cvt_pk_bf16_f32 %0, %1, %2" : "=v"(a)  : "v"(S[e+0]), "v"(S[e+1]));
          asm("v_cvt_pk_bf16_f32 %0, %1, %2" : "=v"(bb) : "v"(S[e+4]), "v"(S[e+5]));
          asm("v_cvt_pk_bf16_f32 %0, %1, %2" : "=v"(cc) : "v"(S[e+2]), "v"(S[e+3]));
          asm("v_cvt_pk_bf16_f32 %0, %1, %2" : "=v"(dd) : "v"(S[e+6]), "v"(S[e+7]));
          asm volatile("v_permlane32_swap_b32 %0, %1" : "+v"(a),  "+v"(bb));
          asm volatile("v_permlane32_swap_b32 %0, %1" : "+v"(cc), "+v"(dd));
          i32x4 pwv; pwv[0] = (int)a; pwv[1] = (int)cc; pwv[2] = (int)bb; pwv[3] = (int)dd;
          paf[kc] = __builtin_bit_cast(bf16x8, pwv);
        }
        __builtin_amdgcn_s_setprio(1);
        #pragma unroll
        for (int kc = 0; kc < 2; ++kc){
          #pragma unroll
          for (int dblk = 0; dblk < 2; ++dblk){
            const int dr = dblk*32 + q31;
            const bf16x8 vf = *(const bf16x8*)(vb + dr*128
                                  + ((((sub<<2)|(kc<<1)|hi) ^ (dr & 7)) << 4));
            O[dblk] = __builtin_amdgcn_mfma_f32_32x32x16_bf16(paf[kc], vf, O[dblk], 0, 0, 0);
          }
        }
        __builtin_amdgcn_s_setprio(0);
      }
    }

    __syncthreads();
    cbuf ^= 1;
  }

  {
    const float lc = l + __shfl_xor(l, 32);
    if (lane < 32) Ls[w][lane] = 1.0f / lc;
  }
  __syncthreads();

  #pragma unroll
  for (int r = 0; r < 16; ++r){
    const int qloc = (r&3) + 8*(r>>2) + 4*hi;
    const float inv = Ls[w][qloc];
    const size_t row = rowB + wq0 + qloc;
    #pragma unroll
    for (int dblk = 0; dblk < 2; ++dblk)
      y[row * CEMB + h*64 + dblk*32 + q31] = f2bf(O[dblk][r] * inv);
  }
  #undef STAGE
}

extern "C" void kernel_launch(void* const* d_in, const int* in_sizes, int n_in,
                              void* d_out, int out_size, void* d_ws, size_t ws_size,
                              hipStream_t stream)
{
  const float* x     = (const float*)d_in[0];
  const float* w_qkv = (const float*)d_in[1];
  const float* b_qkv = (const float*)d_in[2];
  const float* w_out = (const float*)d_in[3];
  const float* b_out = (const float*)d_in[4];
  float* out = (float*)d_out;

  char* ws = (char*)d_ws;
  unsigned short* xb    = (unsigned short*)(ws);                 // 16 MiB; dead after gemm1
  unsigned short* vTb   = (unsigned short*)(ws);                 // 16 MiB (reuses xb)
  unsigned short* qkvb  = (unsigned short*)(ws + (16u<<20));     // 48 MiB [8192,3072]
  unsigned short* yb    = (unsigned short*)(ws + (64u<<20));     // 16 MiB [8192,1024]
  unsigned short* wqkvT = (unsigned short*)(ws + (80u<<20));     //  6 MiB [3072,1024]
  unsigned short* woutT = (unsigned short*)(ws + (86u<<20));     //  2 MiB [1024,1024]

  const int M = 4 * TSEQ; // 8192

  k_cvt_bf16<<<(M * CEMB / 4 + 255) / 256, 256, 0, stream>>>(x, xb, M * CEMB / 4);
  k_transpose_bf16<<<dim3(3072/32, 1024/32), 256, 0, stream>>>(w_qkv, wqkvT, 1024, 3072);
  k_transpose_bf16<<<dim3(1024/32, 1024/32), 256, 0, stream>>>(w_out, woutT, 1024, 1024);

  k_gemm256<true><<<dim3((M/256) * (3072/256)), 512, 0, stream>>>(xb, wqkvT, b_qkv, qkvb, M, 3072, 1024);
  k_vT<<<dim3(64, TSEQ/64), 256, 0, stream>>>(qkvb, vTb);
  k_attn<<<dim3(4 * 16, 8), 512, 0, stream>>>(qkvb, vTb, yb);
  k_gemm_bt<false><<<dim3(1024/128, M/128), 256, 0, stream>>>(yb, woutT, b_out, out, M, 1024, 1024);
}

// Round 8
// 159.160 us; speedup vs baseline: 1.3834x; 1.0506x over previous
//
#include <hip/hip_runtime.h>
#include <hip/hip_bf16.h>

#define TSEQ 2048
#define CEMB 1024

typedef __attribute__((ext_vector_type(8))) short bf16x8;
typedef __attribute__((ext_vector_type(4))) float f32x4;
typedef __attribute__((ext_vector_type(16))) float f32x16;
typedef __attribute__((ext_vector_type(4))) int i32x4;

__device__ __forceinline__ unsigned short f2bf(float f){
  return __builtin_bit_cast(unsigned short, __float2bfloat16(f));
}

__device__ __forceinline__ f32x4 MFMA16(bf16x8 a, bf16x8 b, f32x4 c){
  return __builtin_amdgcn_mfma_f32_16x16x32_bf16(a, b, c, 0, 0, 0);
}

#define GLDS(src, dst) __builtin_amdgcn_global_load_lds( \
      (const __attribute__((address_space(1))) void*)(src), \
      (__attribute__((address_space(3))) void*)(dst), 16, 0, 0)

template<int N> __device__ __forceinline__ void vmwait(){
  if constexpr (N == 0) asm volatile("s_waitcnt vmcnt(0)" ::: "memory");
  else if constexpr (N == 6) asm volatile("s_waitcnt vmcnt(6)" ::: "memory");
  else if constexpr (N == 7) asm volatile("s_waitcnt vmcnt(7)" ::: "memory");
  else asm volatile("s_waitcnt vmcnt(8)" ::: "memory");
}

// ---------- f32 -> bf16 elementwise (4 elems/thread) ----------
__global__ void k_cvt_bf16(const float* __restrict__ in, unsigned short* __restrict__ out, int n4){
  int i = blockIdx.x * blockDim.x + threadIdx.x;
  if (i >= n4) return;
  const float4 v = reinterpret_cast<const float4*>(in)[i];
  ushort4 o;
  o.x = f2bf(v.x); o.y = f2bf(v.y); o.z = f2bf(v.z); o.w = f2bf(v.w);
  reinterpret_cast<ushort4*>(out)[i] = o;
}

// ---------- transpose + convert: w [K,N] f32 -> wT [N,K] bf16 ----------
__global__ void k_transpose_bf16(const float* __restrict__ w, unsigned short* __restrict__ wT, int K, int N){
  __shared__ unsigned short tile[32][33];
  const int n0 = blockIdx.x * 32, k0 = blockIdx.y * 32;
  const int tx = threadIdx.x & 31, ty = threadIdx.x >> 5; // ty 0..7
  #pragma unroll
  for (int r = 0; r < 4; ++r){
    int k = ty * 4 + r;
    tile[k][tx] = f2bf(w[(size_t)(k0 + k) * N + n0 + tx]);
  }
  __syncthreads();
  #pragma unroll
  for (int r = 0; r < 4; ++r){
    int n = ty * 4 + r;
    wT[(size_t)(n0 + n) * K + k0 + tx] = tile[tx][n];
  }
}

// ---------- V head-transpose: qkv[t][2048+h*64+d] -> vT[(bh*64+d)][t] ----------
__global__ __launch_bounds__(256) void k_vT(const unsigned short* __restrict__ qkv,
                                            unsigned short* __restrict__ vT){
  __shared__ __align__(16) unsigned short tile[64*64];
  const int tid = threadIdx.x;
  const int bh = blockIdx.x;          // b*16+h
  const int t0 = blockIdx.y * 64;
  const int b = bh >> 4, h = bh & 15;
  const int lt = tid >> 3, seg = tid & 7;
  #pragma unroll
  for (int r = 0; r < 2; ++r){
    const int t = lt + 32*r;
    const i32x4 v = *(const i32x4*)&qkv[((size_t)(b*TSEQ + t0 + t))*3072 + 2048 + h*64 + seg*8];
    const int slot = seg ^ (t & 7) ^ (t >> 3);
    *(i32x4*)((char*)tile + t*128 + slot*16) = v;
  }
  __syncthreads();
  const int w = tid >> 6, lane = tid & 63;
  const int tseg = lane & 7;
  #pragma unroll
  for (int r = 0; r < 2; ++r){
    const int d = w*8 + (lane>>3) + 32*r;
    unsigned int wd[4];
    #pragma unroll
    for (int jp = 0; jp < 4; ++jp){
      unsigned int lo, hi;
      #pragma unroll
      for (int e = 0; e < 2; ++e){
        const int j = jp*2 + e;
        const int t = tseg*8 + j;
        const int byteoff = t*128 + ((2*d) ^ (((j ^ tseg) & 7) << 4));
        const unsigned int val = *(const unsigned short*)((const char*)tile + byteoff);
        if (e == 0) lo = val; else hi = val;
      }
      wd[jp] = lo | (hi << 16);
    }
    i32x4 o4; o4[0]=wd[0]; o4[1]=wd[1]; o4[2]=wd[2]; o4[3]=wd[3];
    *(i32x4*)&vT[((size_t)bh*64 + d)*2048 + t0 + tseg*8] = o4;
  }
}

// ---------- GEMM 256xBN deep-pipelined (T1+T2+T3+T4+T5) ----------
// 512 thr = 8 waves (2M x 4N); per-wave 128 x BN/4 output; BK=64, two K-tiles
// in flight, raw s_barrier + counted vmcnt(NL) — loads NEVER drain in the
// main loop. LDS content swizzle: chunk ^= row&7 on the global SOURCE
// (linear global_load_lds dest) and on reads. BN chosen for full CU packing.
template<bool OUT_BF16, int BN>
__global__ __launch_bounds__(512, 2) void k_gemm256(
    const unsigned short* __restrict__ A,
    const unsigned short* __restrict__ Bt,
    const float* __restrict__ bias,
    void* __restrict__ Cout, int M, int N, int K)
{
  constexpr int NW  = BN / 64;          // per-wave n-frags AND B-stage insts
  constexpr int NH0 = (NW + 1) / 2;     // n-split for phase scheduling
  constexpr int NL  = 4 + NW;           // loads in flight per K-tile
  constexpr int BNB = BN * 128;         // B buffer bytes per K-tile
  __shared__ __align__(16) char smem[65536 + 2 * BNB];  // A:[2][32K], B:[2][BNB]

  const int tid = threadIdx.x;
  const int lane = tid & 63, w = tid >> 6;      // 8 waves
  const int wm = w >> 2, wn = w & 3;
  const int l15 = lane & 15, l4 = lane >> 4;
  const int x7 = l15 & 7;

  // T1 bijective XCD swizzle (grid % 8 == 0)
  unsigned lin = blockIdx.x;
  {
    const unsigned nwg = gridDim.x;
    const unsigned qq = nwg >> 3, rr = nwg & 7;
    const unsigned xcd = lin & 7, loc = lin >> 3;
    lin = (xcd < rr ? xcd * (qq + 1) : rr * (qq + 1) + (xcd - rr) * qq) + loc;
  }
  const unsigned ntn = (unsigned)N / BN;
  const int m0 = (int)(lin / ntn) << 8;
  const int n0 = (int)(lin % ntn) * BN;

  // staging: inst i covers 64 rows; wave w writes rows w*8..w*8+7 of each
  // group; source content-chunk pre-swizzled (involution cx = sl ^ (row&7)).
  const int srow = lane >> 3;                  // 0..7
  const int scx  = (lane & 7) ^ srow;
  const unsigned short* Ag = A  + (size_t)(m0 + w*8 + srow) * K + scx * 8;
  const unsigned short* Bg = Bt + (size_t)(n0 + w*8 + srow) * K + scx * 8;

  auto stageA = [&](int buf, int kt){
    const unsigned short* s = Ag + kt*64;
    char* d = smem + buf*32768 + (w << 10);
    #pragma unroll
    for (int i = 0; i < 4; ++i) GLDS(s + (size_t)(i*64)*K, d + i*8192);
  };
  auto stageB = [&](int buf, int kt){
    const unsigned short* s = Bg + kt*64;
    char* d = smem + 65536 + buf*BNB + (w << 10);
    #pragma unroll
    for (int i = 0; i < NW; ++i) GLDS(s + (size_t)(i*64)*K, d + i*8192);
  };

  // frag reads: row*128 B + ((chunk ^ (row&7))*16); row&7 == l15&7 == x7
  const int arow = wm*128 + l15;
  const int brow = wn*(BN/4) + l15;
  auto rdA = [&](int buf, int m, int ks)->bf16x8 {
    return *(const bf16x8*)(smem + buf*32768 + (arow + m*16)*128 + (((ks*4 + l4) ^ x7) << 4));
  };
  auto rdB = [&](int buf, int n, int ks)->bf16x8 {
    return *(const bf16x8*)(smem + 65536 + buf*BNB + (brow + n*16)*128 + (((ks*4 + l4) ^ x7) << 4));
  };

  f32x4 acc[8][NW] = {};
  const int NIT = K >> 7;                      // iterations over 2 K-tiles

  stageA(0, 0); stageB(0, 0);
  stageA(1, 1); stageB(1, 1);
  vmwait<NL>();                                // tile 0 landed
  __builtin_amdgcn_s_barrier();
  asm volatile("" ::: "memory");

  for (int it = 0; it < NIT; ++it){
    const bool more = (it + 1 < NIT);
    #pragma unroll
    for (int half = 0; half < 2; ++half){      // K-tile 2it+half lives in buf=half
      const int buf = half;
      bf16x8 bfr[NW][2], af1[4][2], af2[4][2];
      // P1: read all B-frags + A-frags m0..3; compute (m0-3, n<NH0)
      #pragma unroll
      for (int n = 0; n < NW; ++n){ bfr[n][0] = rdB(buf, n, 0); bfr[n][1] = rdB(buf, n, 1); }
      #pragma unroll
      for (int m = 0; m < 4; ++m){ af1[m][0] = rdA(buf, m, 0); af1[m][1] = rdA(buf, m, 1); }
      __builtin_amdgcn_s_setprio(1);
      #pragma unroll
      for (int m = 0; m < 4; ++m)
        #pragma unroll
        for (int n = 0; n < NH0; ++n)
          #pragma unroll
          for (int ks = 0; ks < 2; ++ks)
            acc[m][n] = MFMA16(af1[m][ks], bfr[n][ks], acc[m][n]);
      __builtin_amdgcn_s_setprio(0);
      // P2: read A-frags m4..7; compute (m0-3, n>=NH0)
      #pragma unroll
      for (int m = 0; m < 4; ++m){ af2[m][0] = rdA(buf, m+4, 0); af2[m][1] = rdA(buf, m+4, 1); }
      __builtin_amdgcn_s_setprio(1);
      #pragma unroll
      for (int m = 0; m < 4; ++m)
        #pragma unroll
        for (int n = NH0; n < NW; ++n)
          #pragma unroll
          for (int ks = 0; ks < 2; ++ks)
            acc[m][n] = MFMA16(af1[m][ks], bfr[n][ks], acc[m][n]);
      __builtin_amdgcn_s_setprio(0);
      // P3: compute (m4-7, n>=NH0); drain LDS reads; barrier
      __builtin_amdgcn_s_setprio(1);
      #pragma unroll
      for (int m = 0; m < 4; ++m)
        #pragma unroll
        for (int n = NH0; n < NW; ++n)
          #pragma unroll
          for (int ks = 0; ks < 2; ++ks)
            acc[m+4][n] = MFMA16(af2[m][ks], bfr[n][ks], acc[m+4][n]);
      __builtin_amdgcn_s_setprio(0);
      asm volatile("s_waitcnt lgkmcnt(0)" ::: "memory");
      __builtin_amdgcn_s_barrier();
      asm volatile("" ::: "memory");
      // P4: stage tile (2it+half+2) into this buf; compute (m4-7, n<NH0)
      if (more){ stageA(buf, 2*it + half + 2); stageB(buf, 2*it + half + 2); }
      __builtin_amdgcn_s_setprio(1);
      #pragma unroll
      for (int m = 0; m < 4; ++m)
        #pragma unroll
        for (int n = 0; n < NH0; ++n)
          #pragma unroll
          for (int ks = 0; ks < 2; ++ks)
            acc[m+4][n] = MFMA16(af2[m][ks], bfr[n][ks], acc[m+4][n]);
      __builtin_amdgcn_s_setprio(0);
      if (more) vmwait<NL>();                  // next tile ready
      else      vmwait<0>();
      __builtin_amdgcn_s_barrier();
      asm volatile("" ::: "memory");
    }
  }

  float bv[NW];
  #pragma unroll
  for (int n = 0; n < NW; ++n) bv[n] = bias[n0 + wn*(BN/4) + n*16 + l15];

  #pragma unroll
  for (int m = 0; m < 8; ++m){
    const int row = m0 + wm*128 + m*16 + l4*4;
    #pragma unroll
    for (int n = 0; n < NW; ++n){
      const int col = n0 + wn*(BN/4) + n*16 + l15;
      #pragma unroll
      for (int r = 0; r < 4; ++r){
        float v = acc[m][n][r] + bv[n];
        if (OUT_BF16)
          ((unsigned short*)Cout)[(size_t)(row + r) * N + col] = f2bf(v);
        else
          ((float*)Cout)[(size_t)(row + r) * N + col] = v;
      }
    }
  }
}

// ---------- causal flash attention v6 (unchanged) ----------
__global__ __launch_bounds__(512, 4) void k_attn(
    const unsigned short* __restrict__ qkv,
    const unsigned short* __restrict__ vT,
    unsigned short* __restrict__ y)
{
  __shared__ __align__(16) char Ksm[2][8192];   // [key 64][128B], slot^=(key&7)
  __shared__ __align__(16) char Vsm[2][8192];   // [d 64][128B],  slot^=(d&7)
  __shared__ float Ls[8][32];

  const int tid = threadIdx.x, lane = tid & 63, w = tid >> 6;  // w 0..7
  const int q31 = lane & 31, hi = lane >> 5;
  const int bh = blockIdx.x, p = blockIdx.y;    // p in [0,8)
  const int g = w >> 2, wl = w & 3;
  const int myt = g ? (15 - p) : p;             // this wavegroup's q-tile
  const int b = bh >> 4, h = bh & 15;
  const size_t rowB = (size_t)b * TSEQ;

  const int wq0 = myt*128 + 32*wl, qg = wq0 + q31;
  const int nkt_my = 2*myt + 2;
  const int nktB  = 2*(15 - p) + 2;

  const float sc = 0.18033688011112042f;   // (1/sqrt(64)) * log2(e)

  bf16x8 qf[4];
  {
    const unsigned short* qp = qkv + (rowB + qg) * 3072 + h * 64;
    #pragma unroll
    for (int c4 = 0; c4 < 4; ++c4){
      bf16x8 v = *(const bf16x8*)(qp + c4*16 + hi*8);
      #pragma unroll
      for (int j = 0; j < 8; ++j){
        const unsigned int bits = ((unsigned int)(unsigned short)v[j]) << 16;
        v[j] = (short)f2bf(__builtin_bit_cast(float, bits) * sc);
      }
      qf[c4] = v;
    }
  }

  const int kr = lane >> 3, sl = lane & 7, cx = sl ^ kr;
  const unsigned short* kgbase = qkv + (rowB + w*8 + kr) * 3072 + 1024 + h*64 + cx*8;
  const unsigned short* vgbase = vT + ((size_t)bh*64 + w*8 + kr) * 2048 + cx*8;

  #define STAGE(ktile, buf)                                                          \
    do {                                                                             \
      GLDS(kgbase + (size_t)(ktile)*64*3072, &Ksm[buf][0] + w*1024);                 \
      GLDS(vgbase + (ktile)*64,              &Vsm[buf][0] + w*1024);                 \
    } while (0)

  f32x16 O[2] = {};
  float l = 0.f;

  STAGE(0, 0);
  __syncthreads();

  int cbuf = 0;
  for (int kt = 0; kt < nktB; ++kt){
    if (kt + 1 < nktB) STAGE(kt + 1, cbuf ^ 1);

    if (kt < nkt_my){
      const char* kb = Ksm[cbuf];
      const char* vb = Vsm[cbuf];
      const bool domask = (kt*64 + 63 > wq0);
      #pragma unroll
      for (int sub = 0; sub < 2; ++sub){
        f32x16 S = {};
        __builtin_amdgcn_s_setprio(1);
        #pragma unroll
        for (int c4 = 0; c4 < 4; ++c4){
          const bf16x8 kf = *(const bf16x8*)(kb + (sub*32 + q31)*128
                                + ((((c4<<1)|hi) ^ (q31 & 7)) << 4));
          S = __builtin_amdgcn_mfma_f32_32x32x16_bf16(kf, qf[c4], S, 0, 0, 0);
        }
        __builtin_amdgcn_s_setprio(0);
        if (domask){
          #pragma unroll
          for (int r = 0; r < 16; ++r){
            const int kg = kt*64 + sub*32 + (r&3) + 8*(r>>2) + 4*hi;
            if (kg > qg) S[r] = -1e30f;
          }
        }
        float ps = 0.f;
        #pragma unroll
        for (int r = 0; r < 16; ++r){
          S[r] = __builtin_amdgcn_exp2f(S[r]);
          ps += S[r];
        }
        l += ps;
        bf16x8 paf[2];
        #pragma unroll
        for (int kc = 0; kc < 2; ++kc){
          const int e = kc * 8;
          unsigned int a, bb, cc, dd;
          asm("v_cvt_pk_bf16_f32 %0, %1, %2" : "=v"(a)  : "v"(S[e+0]), "v"(S[e+1]));
          asm("v_cvt_pk_bf16_f32 %0, %1, %2" : "=v"(bb) : "v"(S[e+4]), "v"(S[e+5]));
          asm("v_cvt_pk_bf16_f32 %0, %1, %2" : "=v"(cc) : "v"(S[e+2]), "v"(S[e+3]));
          asm("v_cvt_pk_bf16_f32 %0, %1, %2" : "=v"(dd) : "v"(S[e+6]), "v"(S[e+7]));
          asm volatile("v_permlane32_swap_b32 %0, %1" : "+v"(a),  "+v"(bb));
          asm volatile("v_permlane32_swap_b32 %0, %1" : "+v"(cc), "+v"(dd));
          i32x4 pwv; pwv[0] = (int)a; pwv[1] = (int)cc; pwv[2] = (int)bb; pwv[3] = (int)dd;
          paf[kc] = __builtin_bit_cast(bf16x8, pwv);
        }
        __builtin_amdgcn_s_setprio(1);
        #pragma unroll
        for (int kc = 0; kc < 2; ++kc){
          #pragma unroll
          for (int dblk = 0; dblk < 2; ++dblk){
            const int dr = dblk*32 + q31;
            const bf16x8 vf = *(const bf16x8*)(vb + dr*128
                                  + ((((sub<<2)|(kc<<1)|hi) ^ (dr & 7)) << 4));
            O[dblk] = __builtin_amdgcn_mfma_f32_32x32x16_bf16(paf[kc], vf, O[dblk], 0, 0, 0);
          }
        }
        __builtin_amdgcn_s_setprio(0);
      }
    }

    __syncthreads();
    cbuf ^= 1;
  }

  {
    const float lc = l + __shfl_xor(l, 32);
    if (lane < 32) Ls[w][lane] = 1.0f / lc;
  }
  __syncthreads();

  #pragma unroll
  for (int r = 0; r < 16; ++r){
    const int qloc = (r&3) + 8*(r>>2) + 4*hi;
    const float inv = Ls[w][qloc];
    const size_t row = rowB + wq0 + qloc;
    #pragma unroll
    for (int dblk = 0; dblk < 2; ++dblk)
      y[row * CEMB + h*64 + dblk*32 + q31] = f2bf(O[dblk][r] * inv);
  }
  #undef STAGE
}

extern "C" void kernel_launch(void* const* d_in, const int* in_sizes, int n_in,
                              void* d_out, int out_size, void* d_ws, size_t ws_size,
                              hipStream_t stream)
{
  const float* x     = (const float*)d_in[0];
  const float* w_qkv = (const float*)d_in[1];
  const float* b_qkv = (const float*)d_in[2];
  const float* w_out = (const float*)d_in[3];
  const float* b_out = (const float*)d_in[4];
  float* out = (float*)d_out;

  char* ws = (char*)d_ws;
  unsigned short* xb    = (unsigned short*)(ws);                 // 16 MiB; dead after gemm1
  unsigned short* vTb   = (unsigned short*)(ws);                 // 16 MiB (reuses xb)
  unsigned short* qkvb  = (unsigned short*)(ws + (16u<<20));     // 48 MiB [8192,3072]
  unsigned short* yb    = (unsigned short*)(ws + (64u<<20));     // 16 MiB [8192,1024]
  unsigned short* wqkvT = (unsigned short*)(ws + (80u<<20));     //  6 MiB [3072,1024]
  unsigned short* woutT = (unsigned short*)(ws + (86u<<20));     //  2 MiB [1024,1024]

  const int M = 4 * TSEQ; // 8192

  k_cvt_bf16<<<(M * CEMB / 4 + 255) / 256, 256, 0, stream>>>(x, xb, M * CEMB / 4);
  k_transpose_bf16<<<dim3(3072/32, 1024/32), 256, 0, stream>>>(w_qkv, wqkvT, 1024, 3072);
  k_transpose_bf16<<<dim3(1024/32, 1024/32), 256, 0, stream>>>(w_out, woutT, 1024, 1024);

  // QKV: 256x192 tiles -> 32*16 = 512 blocks = 2 full CU rounds
  k_gemm256<true, 192><<<dim3((M/256) * (3072/192)), 512, 0, stream>>>(xb, wqkvT, b_qkv, qkvb, M, 3072, 1024);
  k_vT<<<dim3(64, TSEQ/64), 256, 0, stream>>>(qkvb, vTb);
  k_attn<<<dim3(4 * 16, 8), 512, 0, stream>>>(qkvb, vTb, yb);
  // out-proj: 256x128 tiles -> 32*8 = 256 blocks = 1 full CU round
  k_gemm256<false, 128><<<dim3((M/256) * (1024/128)), 512, 0, stream>>>(yb, woutT, b_out, out, M, 1024, 1024);
}